// Round 7
// baseline (229.965 us; speedup 1.0000x reference)
//
#include <hip/hip_runtime.h>
#include <hip/hip_bf16.h>

#define NREL 8
#define CH   64   // IN_CH == HID_CH == 64

typedef unsigned int uint32;

// ---- bf16 helpers (RNE) ----------------------------------------------------
static __device__ __forceinline__ uint32 packbf(float a, float b) {
    uint32 ua = __float_as_uint(a), ub = __float_as_uint(b);
    ua = (ua + 0x7fffu + ((ua >> 16) & 1u)) >> 16;          // low half  (elem 0)
    ub = (ub + 0x7fffu + ((ub >> 16) & 1u)) & 0xffff0000u;  // high half (elem 1)
    return ua | ub;
}
static __device__ __forceinline__ float bflo(uint32 w) { return __uint_as_float(w << 16); }
static __device__ __forceinline__ float bfhi(uint32 w) { return __uint_as_float(w & 0xffff0000u); }

// ---------------------------------------------------------------------------
// xbf[n][cp] = packed bf16 pair of x[n][2cp..2cp+1]  (cp = 0..31)
// ---------------------------------------------------------------------------
__global__ __launch_bounds__(256) void xbf_k(
    const float* __restrict__ x, uint32* __restrict__ xbf, int n2)
{
    const int i = blockIdx.x * 256 + threadIdx.x;
    if (i < n2) {
        const float2 v = ((const float2*)x)[i];
        xbf[i] = packbf(v.x, v.y);
    }
}

// ---------------------------------------------------------------------------
// Coarse histogram over c = dst>>8 (NC buckets). LDS-staged.
// ---------------------------------------------------------------------------
__global__ __launch_bounds__(256) void chist_k(
    const int* __restrict__ ei, int* __restrict__ ccnt, int nE, int nT)
{
    __shared__ int h[256];
    h[threadIdx.x] = 0;
    __syncthreads();
    for (int e = blockIdx.x * 256 + threadIdx.x; e < nE; e += nT)
        atomicAdd(&h[ei[nE + e] >> 8], 1);
    __syncthreads();
    const int c = threadIdx.x;
    if (h[c]) atomicAdd(&ccnt[c], h[c]);
}

// ---------------------------------------------------------------------------
// Coarse exclusive scan (NC <= 256), fills cbase[0..NC] and ccur.
// ---------------------------------------------------------------------------
__global__ __launch_bounds__(256) void cscan_k(
    const int* __restrict__ ccnt, int* __restrict__ cbase,
    int* __restrict__ ccur, int NC)
{
    __shared__ int sc[256];
    const int t = threadIdx.x;
    const int v = (t < NC) ? ccnt[t] : 0;
    sc[t] = v;
    __syncthreads();
    for (int off = 1; off < 256; off <<= 1) {
        int add = (t >= off) ? sc[t - off] : 0;
        __syncthreads();
        sc[t] += add;
        __syncthreads();
    }
    const int ex = sc[t] - v;
    if (t < NC) { cbase[t] = ex; ccur[t] = ex; }
    if (t == 255) cbase[NC] = sc[255];
}

// ---------------------------------------------------------------------------
// Coarse binning: per 2048-edge chunk, stage in LDS, reserve runs, write runs.
// Entry pack: (dlow<<24)|(rel<<16)|src.
// ---------------------------------------------------------------------------
__global__ __launch_bounds__(256) void bin_k(
    const int* __restrict__ ei, const int* __restrict__ rel,
    int* __restrict__ ccur, uint32* __restrict__ binned, int nE)
{
    __shared__ uint32        ent[2048];
    __shared__ unsigned char cid[2048];
    __shared__ int lh[256], lb[256], lc[256];

    const int t = threadIdx.x;
    lh[t] = 0;
    __syncthreads();

    const int base = blockIdx.x * 2048;
    #pragma unroll
    for (int i = 0; i < 8; ++i) {
        const int idx = t + i * 256;
        const int e   = base + idx;
        if (e < nE) {
            const int dst = ei[nE + e];
            ent[idx] = ((uint32)(dst & 255) << 24) | ((uint32)rel[e] << 16) | (uint32)ei[e];
            const int c = dst >> 8;
            cid[idx] = (unsigned char)c;
            atomicAdd(&lh[c], 1);
        } else {
            cid[idx] = 255;   // sentinel (NC <= 254 guard in launcher)
        }
    }
    __syncthreads();

    if (lh[t]) lb[t] = atomicAdd(&ccur[t], lh[t]);
    lc[t] = 0;
    __syncthreads();

    #pragma unroll
    for (int i = 0; i < 8; ++i) {
        const int idx = t + i * 256;
        const int c   = cid[idx];
        if (c != 255) {
            const int off = atomicAdd(&lc[c], 1);
            binned[lb[c] + off] = ent[idx];
        }
    }
}

// ---------------------------------------------------------------------------
// Fine sort within one coarse bucket (keyspace 2048 = dlow*8+rel), in LDS.
// ---------------------------------------------------------------------------
__global__ __launch_bounds__(1024) void fsort_k(
    const uint32* __restrict__ binned, const int* __restrict__ cbase,
    int* __restrict__ start, int* __restrict__ sorted, int NC)
{
    __shared__ int fh[2048], fex[2048], fcur[2048], sc[1024];
    const int c  = blockIdx.x;
    const int t  = threadIdx.x;
    const int n0 = cbase[c];
    const int n1 = cbase[c + 1];

    fh[t] = 0; fh[t + 1024] = 0;
    __syncthreads();

    for (int j = n0 + t; j < n1; j += 1024) {
        const uint32 en = binned[j];
        atomicAdd(&fh[((en >> 24) << 3) | ((en >> 16) & 7)], 1);
    }
    __syncthreads();

    const int a = fh[2 * t], b = fh[2 * t + 1];
    sc[t] = a + b;
    __syncthreads();
    for (int off = 1; off < 1024; off <<= 1) {
        int add = (t >= off) ? sc[t - off] : 0;
        __syncthreads();
        sc[t] += add;
        __syncthreads();
    }
    const int ep = sc[t] - (a + b);
    fex[2 * t] = ep; fex[2 * t + 1] = ep + a;
    __syncthreads();

    fcur[t] = fex[t]; fcur[t + 1024] = fex[t + 1024];
    {
        const int k0 = c << 11;
        start[k0 + t]        = n0 + fex[t];
        start[k0 + t + 1024] = n0 + fex[t + 1024];
    }
    if (c == NC - 1 && t == 0) start[NC << 11] = n1;
    __syncthreads();

    for (int j = n0 + t; j < n1; j += 1024) {
        const uint32 en = binned[j];
        const int fk  = ((en >> 24) << 3) | ((en >> 16) & 7);
        const int off = atomicAdd(&fcur[fk], 1);
        sorted[n0 + off] = (int)(en & 0xFFFFu);
    }
}

// ---------------------------------------------------------------------------
// Aggregate v3: one wave per dst node, halves split each segment (even/odd),
// lane%32 = channel pair. All 9 segment boundaries loaded up front; rel loop
// FULLY UNROLLED with 8 independent accumulator pairs so the compiler can
// put all 8 gather chains in flight (was serialized -> latency-bound).
// ---------------------------------------------------------------------------
__global__ __launch_bounds__(256) void agg_k(
    const uint32* __restrict__ xbf, const int* __restrict__ start,
    const int* __restrict__ sorted, uint32* __restrict__ A, int nN)
{
    const int n = (int)((blockIdx.x * 256u + threadIdx.x) >> 6);
    if (n >= nN) return;
    const int l32  = threadIdx.x & 31;
    const int half = (threadIdx.x >> 5) & 1;
    const int kb   = n * NREL;

    // Batched boundary load: start[kb..kb+8] (kb is 8-aligned).
    const int4 s0 = *(const int4*)(start + kb);
    const int4 s1 = *(const int4*)(start + kb + 4);
    const int  s8 = start[kb + 8];
    const int bnd[9] = { s0.x, s0.y, s0.z, s0.w, s1.x, s1.y, s1.z, s1.w, s8 };

    float a0[NREL], a1[NREL];
    #pragma unroll
    for (int r = 0; r < NREL; ++r) {
        a0[r] = 0.f; a1[r] = 0.f;
        for (int j = bnd[r] + half; j < bnd[r + 1]; j += 2) {
            const uint32 u = xbf[(size_t)sorted[j] * 32 + l32];
            a0[r] += bflo(u); a1[r] += bfhi(u);
        }
    }

    #pragma unroll
    for (int r = 0; r < NREL; ++r) {
        float v0 = a0[r] + __shfl_xor(a0[r], 32);
        float v1 = a1[r] + __shfl_xor(a1[r], 32);
        if (half == 0)
            A[(size_t)(kb + r) * 32 + l32] = packbf(v0, v1);
    }
}

// ---------------------------------------------------------------------------
// GEMM: out[nN,64] = A[nN,512](bf16) @ Wf[512,64](fp32). 64x64 tile, K=128 chunks.
// ---------------------------------------------------------------------------
__global__ __launch_bounds__(256, 2) void gemm_k(
    const uint32* __restrict__ A, const float* __restrict__ Wf,
    float* __restrict__ out, int nN)
{
    __shared__ float AT[128 * 64];   // [k][n] 32 KB
    __shared__ float WC[128 * 64];   // [k][h] 32 KB

    const int t      = threadIdx.x;
    const int n_base = blockIdx.x * 64;
    const int n_l    = t & 63;
    const int q      = t >> 6;
    const int tn     = t >> 4;
    const int th     = t & 15;

    float acc[4][4];
    #pragma unroll
    for (int a = 0; a < 4; ++a)
        #pragma unroll
        for (int b = 0; b < 4; ++b) acc[a][b] = 0.f;

    for (int kc = 0; kc < 512; kc += 128) {
        {
            const int n  = n_base + n_l;
            const int kb = q * 32;
            if (n < nN) {
                const uint32* ap = A + (size_t)n * 256 + ((kc + kb) >> 1);
                #pragma unroll
                for (int m = 0; m < 4; ++m) {
                    const uint4 u = *(const uint4*)(ap + m * 4);   // 8 bf16
                    const int kk = kb + m * 8;
                    AT[(kk + 0) * 64 + n_l] = bflo(u.x);
                    AT[(kk + 1) * 64 + n_l] = bfhi(u.x);
                    AT[(kk + 2) * 64 + n_l] = bflo(u.y);
                    AT[(kk + 3) * 64 + n_l] = bfhi(u.y);
                    AT[(kk + 4) * 64 + n_l] = bflo(u.z);
                    AT[(kk + 5) * 64 + n_l] = bfhi(u.z);
                    AT[(kk + 6) * 64 + n_l] = bflo(u.w);
                    AT[(kk + 7) * 64 + n_l] = bfhi(u.w);
                }
            } else {
                #pragma unroll
                for (int m = 0; m < 32; ++m) AT[(kb + m) * 64 + n_l] = 0.f;
            }
        }
        {
            const float* wsrc = Wf + (kc << 6);
            #pragma unroll
            for (int j = 0; j < 8; ++j) {
                const int idx = (t << 2) + (j << 10);
                *(float4*)(WC + idx) = *(const float4*)(wsrc + idx);
            }
        }
        __syncthreads();

        #pragma unroll 8
        for (int i = 0; i < 128; ++i) {
            const float4 av = *(const float4*)(AT + i * 64 + (tn << 2));
            const float4 bv = *(const float4*)(WC + i * 64 + (th << 2));
            acc[0][0] += av.x * bv.x; acc[0][1] += av.x * bv.y;
            acc[0][2] += av.x * bv.z; acc[0][3] += av.x * bv.w;
            acc[1][0] += av.y * bv.x; acc[1][1] += av.y * bv.y;
            acc[1][2] += av.y * bv.z; acc[1][3] += av.y * bv.w;
            acc[2][0] += av.z * bv.x; acc[2][1] += av.z * bv.y;
            acc[2][2] += av.z * bv.z; acc[2][3] += av.z * bv.w;
            acc[3][0] += av.w * bv.x; acc[3][1] += av.w * bv.y;
            acc[3][2] += av.w * bv.z; acc[3][3] += av.w * bv.w;
        }
        __syncthreads();
    }

    #pragma unroll
    for (int dn = 0; dn < 4; ++dn) {
        const int n = n_base + (tn << 2) + dn;
        if (n < nN) {
            float4 o;
            o.x = acc[dn][0]; o.y = acc[dn][1]; o.z = acc[dn][2]; o.w = acc[dn][3];
            *(float4*)(out + (size_t)n * CH + (th << 2)) = o;
        }
    }
}

// ---------------------------------------------------------------------------
// Fallback: per-edge direct with atomics.
// ---------------------------------------------------------------------------
__global__ __launch_bounds__(256) void rgcn_direct_kernel(
    const float* __restrict__ x, const float* __restrict__ W,
    const int* __restrict__ ei, const int* __restrict__ rel,
    float* __restrict__ out, int nE, int nWaves)
{
    const int w    = (int)((blockIdx.x * 256u + threadIdx.x) >> 6);
    const int lane = threadIdx.x & 63;

    for (int e = w; e < nE; e += nWaves) {
        const int src = ei[e];
        const int dst = ei[nE + e];
        const int r   = rel[e];
        const float* xrow = x + (size_t)src * CH;
        const float* wcol = W + ((size_t)r << 12) + lane;
        float acc = 0.f;
        #pragma unroll
        for (int i = 0; i < CH; ++i) acc += xrow[i] * wcol[i * CH];
        atomicAdd(out + (size_t)dst * CH + lane, acc);
    }
}

static inline size_t align256(size_t v) { return (v + 255) & ~(size_t)255; }

extern "C" void kernel_launch(void* const* d_in, const int* in_sizes, int n_in,
                              void* d_out, int out_size, void* d_ws, size_t ws_size,
                              hipStream_t stream) {
    const float* x   = (const float*)d_in[0];
    const float* W   = (const float*)d_in[1];
    const int*   ei  = (const int*)d_in[2];
    const int*   rel = (const int*)d_in[3];
    float*       out = (float*)d_out;

    const int nN = in_sizes[0] / CH;   // 50000
    const int nE = in_sizes[3];        // 1000000
    const int nK = nN * NREL;          // 400000
    const int NC = (nN + 255) >> 8;    // 196 coarse buckets

    // Workspace layout
    const size_t sz_A      = align256((size_t)nK * 32 * sizeof(uint32));        // 51.2 MB
    const size_t sz_xbf    = align256((size_t)nN * 32 * sizeof(uint32));        // 6.4 MB
    const size_t sz_start  = align256(((size_t)NC * 2048 + 2) * sizeof(int));   // 1.6 MB
    const size_t sz_binned = align256((size_t)nE * sizeof(uint32));             // 4 MB
    const size_t sz_sorted = align256((size_t)nE * sizeof(int));                // 4 MB
    const size_t sz_ccnt   = align256(256 * sizeof(int));
    const size_t sz_cbase  = align256(257 * sizeof(int));
    const size_t sz_ccur   = align256(256 * sizeof(int));
    const size_t need = sz_A + sz_xbf + sz_start + sz_binned + sz_sorted +
                        sz_ccnt + sz_cbase + sz_ccur;

    if (ws_size >= need && nN <= 65024 && NC <= 254) {
        char* p = (char*)d_ws;
        uint32* A      = (uint32*)p;  p += sz_A;
        uint32* xbf    = (uint32*)p;  p += sz_xbf;
        int*    start  = (int*)p;     p += sz_start;
        uint32* binned = (uint32*)p;  p += sz_binned;
        int*    sorted = (int*)p;     p += sz_sorted;
        int*    ccnt   = (int*)p;     p += sz_ccnt;
        int*    cbase  = (int*)p;     p += sz_cbase;
        int*    ccur   = (int*)p;

        hipMemsetAsync(ccnt, 0, 256 * sizeof(int), stream);

        const int n2 = nN * 32;
        xbf_k<<<(n2 + 255) / 256, 256, 0, stream>>>(x, xbf, n2);

        chist_k<<<256, 256, 0, stream>>>(ei, ccnt, nE, 256 * 256);
        cscan_k<<<1, 256, 0, stream>>>(ccnt, cbase, ccur, NC);
        bin_k<<<(nE + 2047) / 2048, 256, 0, stream>>>(ei, rel, ccur, binned, nE);
        fsort_k<<<NC, 1024, 0, stream>>>(binned, cbase, start, sorted, NC);

        const int aggBlocks = (nN + 3) / 4;
        agg_k<<<aggBlocks, 256, 0, stream>>>(xbf, start, sorted, A, nN);

        gemm_k<<<(nN + 63) / 64, 256, 0, stream>>>(A, W, out, nN);
    } else {
        hipMemsetAsync(out, 0, (size_t)out_size * sizeof(float), stream);
        const int blocks = 2048;
        const int nWaves = blocks * (256 / 64);
        rgcn_direct_kernel<<<blocks, 256, 0, stream>>>(x, W, ei, rel, out, nE, nWaves);
    }
}

// Round 8
// 147.937 us; speedup vs baseline: 1.5545x; 1.5545x over previous
//
#include <hip/hip_runtime.h>
#include <hip/hip_bf16.h>

#define NREL 8
#define CH   64   // IN_CH == HID_CH == 64

typedef unsigned int uint32;

// ---- bf16 helpers (RNE) ----------------------------------------------------
static __device__ __forceinline__ uint32 packbf(float a, float b) {
    uint32 ua = __float_as_uint(a), ub = __float_as_uint(b);
    ua = (ua + 0x7fffu + ((ua >> 16) & 1u)) >> 16;          // low half  (elem 0)
    ub = (ub + 0x7fffu + ((ub >> 16) & 1u)) & 0xffff0000u;  // high half (elem 1)
    return ua | ub;
}
static __device__ __forceinline__ float bflo(uint32 w) { return __uint_as_float(w << 16); }
static __device__ __forceinline__ float bfhi(uint32 w) { return __uint_as_float(w & 0xffff0000u); }

// ---------------------------------------------------------------------------
// xbf[n][cp] = packed bf16 pair of x[n][2cp..2cp+1]  (cp = 0..31)
// ---------------------------------------------------------------------------
__global__ __launch_bounds__(256) void xbf_k(
    const float* __restrict__ x, uint32* __restrict__ xbf, int n2)
{
    const int i = blockIdx.x * 256 + threadIdx.x;
    if (i < n2) {
        const float2 v = ((const float2*)x)[i];
        xbf[i] = packbf(v.x, v.y);
    }
}

// ---------------------------------------------------------------------------
// Coarse histogram over c = dst>>8 (NC buckets). LDS-staged.
// ---------------------------------------------------------------------------
__global__ __launch_bounds__(256) void chist_k(
    const int* __restrict__ ei, int* __restrict__ ccnt, int nE, int nT)
{
    __shared__ int h[256];
    h[threadIdx.x] = 0;
    __syncthreads();
    for (int e = blockIdx.x * 256 + threadIdx.x; e < nE; e += nT)
        atomicAdd(&h[ei[nE + e] >> 8], 1);
    __syncthreads();
    const int c = threadIdx.x;
    if (h[c]) atomicAdd(&ccnt[c], h[c]);
}

// ---------------------------------------------------------------------------
// Coarse exclusive scan (NC <= 256), fills cbase[0..NC] and ccur.
// ---------------------------------------------------------------------------
__global__ __launch_bounds__(256) void cscan_k(
    const int* __restrict__ ccnt, int* __restrict__ cbase,
    int* __restrict__ ccur, int NC)
{
    __shared__ int sc[256];
    const int t = threadIdx.x;
    const int v = (t < NC) ? ccnt[t] : 0;
    sc[t] = v;
    __syncthreads();
    for (int off = 1; off < 256; off <<= 1) {
        int add = (t >= off) ? sc[t - off] : 0;
        __syncthreads();
        sc[t] += add;
        __syncthreads();
    }
    const int ex = sc[t] - v;
    if (t < NC) { cbase[t] = ex; ccur[t] = ex; }
    if (t == 255) cbase[NC] = sc[255];
}

// ---------------------------------------------------------------------------
// Coarse binning: per 2048-edge chunk, stage in LDS, reserve runs, write runs.
// Entry pack: (dlow<<24)|(rel<<16)|src.
// ---------------------------------------------------------------------------
__global__ __launch_bounds__(256) void bin_k(
    const int* __restrict__ ei, const int* __restrict__ rel,
    int* __restrict__ ccur, uint32* __restrict__ binned, int nE)
{
    __shared__ uint32        ent[2048];
    __shared__ unsigned char cid[2048];
    __shared__ int lh[256], lb[256], lc[256];

    const int t = threadIdx.x;
    lh[t] = 0;
    __syncthreads();

    const int base = blockIdx.x * 2048;
    #pragma unroll
    for (int i = 0; i < 8; ++i) {
        const int idx = t + i * 256;
        const int e   = base + idx;
        if (e < nE) {
            const int dst = ei[nE + e];
            ent[idx] = ((uint32)(dst & 255) << 24) | ((uint32)rel[e] << 16) | (uint32)ei[e];
            const int c = dst >> 8;
            cid[idx] = (unsigned char)c;
            atomicAdd(&lh[c], 1);
        } else {
            cid[idx] = 255;   // sentinel (NC <= 254 guard in launcher)
        }
    }
    __syncthreads();

    if (lh[t]) lb[t] = atomicAdd(&ccur[t], lh[t]);
    lc[t] = 0;
    __syncthreads();

    #pragma unroll
    for (int i = 0; i < 8; ++i) {
        const int idx = t + i * 256;
        const int c   = cid[idx];
        if (c != 255) {
            const int off = atomicAdd(&lc[c], 1);
            binned[lb[c] + off] = ent[idx];
        }
    }
}

// ---------------------------------------------------------------------------
// Fine sort within one coarse bucket (keyspace 2048 = dlow*8+rel), in LDS.
// sorted[] entries keep (rel<<16)|src so the aggregator can flush on
// rel-change without reloading segment boundaries.
// ---------------------------------------------------------------------------
__global__ __launch_bounds__(1024) void fsort_k(
    const uint32* __restrict__ binned, const int* __restrict__ cbase,
    int* __restrict__ start, int* __restrict__ sorted, int NC)
{
    __shared__ int fh[2048], fex[2048], fcur[2048], sc[1024];
    const int c  = blockIdx.x;
    const int t  = threadIdx.x;
    const int n0 = cbase[c];
    const int n1 = cbase[c + 1];

    fh[t] = 0; fh[t + 1024] = 0;
    __syncthreads();

    for (int j = n0 + t; j < n1; j += 1024) {
        const uint32 en = binned[j];
        atomicAdd(&fh[((en >> 24) << 3) | ((en >> 16) & 7)], 1);
    }
    __syncthreads();

    const int a = fh[2 * t], b = fh[2 * t + 1];
    sc[t] = a + b;
    __syncthreads();
    for (int off = 1; off < 1024; off <<= 1) {
        int add = (t >= off) ? sc[t - off] : 0;
        __syncthreads();
        sc[t] += add;
        __syncthreads();
    }
    const int ep = sc[t] - (a + b);
    fex[2 * t] = ep; fex[2 * t + 1] = ep + a;
    __syncthreads();

    fcur[t] = fex[t]; fcur[t + 1024] = fex[t + 1024];
    {
        const int k0 = c << 11;
        start[k0 + t]        = n0 + fex[t];
        start[k0 + t + 1024] = n0 + fex[t + 1024];
    }
    if (c == NC - 1 && t == 0) start[NC << 11] = n1;
    __syncthreads();

    for (int j = n0 + t; j < n1; j += 1024) {
        const uint32 en = binned[j];
        const int fk  = ((en >> 24) << 3) | ((en >> 16) & 7);
        const int off = atomicAdd(&fcur[fk], 1);
        sorted[n0 + off] = (int)(en & 0x7FFFFu);   // (rel<<16)|src
    }
}

// ---------------------------------------------------------------------------
// Aggregate v4: one HALF-WAVE per dst node, lane%32 = channel pair.
// The node's whole edge range [start[kb], start[kb+8]) is ONE flat loop,
// manually 4-unrolled (4 gathers in flight). Single accumulator pair,
// flush-on-rel-change (all flush logic is half-wave-uniform; no dynamic
// register indexing). Unseen rels get static zero-stores at the end.
// ---------------------------------------------------------------------------
#define AGG_PROCESS(eu, uu)                                            \
    {                                                                  \
        const int r_ = (int)((eu) >> 16);                              \
        if (r_ != prev) {                                              \
            if (prev >= 0)                                             \
                A[(size_t)(kb + prev) * 32 + l32] = packbf(a0, a1);    \
            a0 = 0.f; a1 = 0.f;                                        \
            prev = r_;                                                 \
            seen |= (1u << r_);                                        \
        }                                                              \
        a0 += bflo(uu); a1 += bfhi(uu);                                \
    }

__global__ __launch_bounds__(256) void agg_k(
    const uint32* __restrict__ xbf, const int* __restrict__ start,
    const int* __restrict__ sorted, uint32* __restrict__ A, int nN)
{
    const int n = (int)((blockIdx.x * 256u + threadIdx.x) >> 5);   // half-wave id
    if (n >= nN) return;
    const int l32 = threadIdx.x & 31;
    const int kb  = n * NREL;

    const int b0 = start[kb];
    const int b8 = start[kb + 8];

    int   prev = -1;
    float a0 = 0.f, a1 = 0.f;
    unsigned seen = 0;

    int j = b0;
    for (; j + 4 <= b8; j += 4) {
        const uint32 e0 = (uint32)sorted[j];
        const uint32 e1 = (uint32)sorted[j + 1];
        const uint32 e2 = (uint32)sorted[j + 2];
        const uint32 e3 = (uint32)sorted[j + 3];
        const uint32 u0 = xbf[(size_t)(e0 & 0xFFFFu) * 32 + l32];
        const uint32 u1 = xbf[(size_t)(e1 & 0xFFFFu) * 32 + l32];
        const uint32 u2 = xbf[(size_t)(e2 & 0xFFFFu) * 32 + l32];
        const uint32 u3 = xbf[(size_t)(e3 & 0xFFFFu) * 32 + l32];
        AGG_PROCESS(e0, u0);
        AGG_PROCESS(e1, u1);
        AGG_PROCESS(e2, u2);
        AGG_PROCESS(e3, u3);
    }
    for (; j < b8; ++j) {
        const uint32 e = (uint32)sorted[j];
        const uint32 u = xbf[(size_t)(e & 0xFFFFu) * 32 + l32];
        AGG_PROCESS(e, u);
    }

    if (prev >= 0)
        A[(size_t)(kb + prev) * 32 + l32] = packbf(a0, a1);

    #pragma unroll
    for (int r = 0; r < NREL; ++r)
        if (!(seen & (1u << r)))
            A[(size_t)(kb + r) * 32 + l32] = 0u;
}

// ---------------------------------------------------------------------------
// GEMM: out[nN,64] = A[nN,512](bf16) @ Wf[512,64](fp32). 64x64 tile, K=128 chunks.
// ---------------------------------------------------------------------------
__global__ __launch_bounds__(256, 2) void gemm_k(
    const uint32* __restrict__ A, const float* __restrict__ Wf,
    float* __restrict__ out, int nN)
{
    __shared__ float AT[128 * 64];   // [k][n] 32 KB
    __shared__ float WC[128 * 64];   // [k][h] 32 KB

    const int t      = threadIdx.x;
    const int n_base = blockIdx.x * 64;
    const int n_l    = t & 63;
    const int q      = t >> 6;
    const int tn     = t >> 4;
    const int th     = t & 15;

    float acc[4][4];
    #pragma unroll
    for (int a = 0; a < 4; ++a)
        #pragma unroll
        for (int b = 0; b < 4; ++b) acc[a][b] = 0.f;

    for (int kc = 0; kc < 512; kc += 128) {
        {
            const int n  = n_base + n_l;
            const int kb = q * 32;
            if (n < nN) {
                const uint32* ap = A + (size_t)n * 256 + ((kc + kb) >> 1);
                #pragma unroll
                for (int m = 0; m < 4; ++m) {
                    const uint4 u = *(const uint4*)(ap + m * 4);   // 8 bf16
                    const int kk = kb + m * 8;
                    AT[(kk + 0) * 64 + n_l] = bflo(u.x);
                    AT[(kk + 1) * 64 + n_l] = bfhi(u.x);
                    AT[(kk + 2) * 64 + n_l] = bflo(u.y);
                    AT[(kk + 3) * 64 + n_l] = bfhi(u.y);
                    AT[(kk + 4) * 64 + n_l] = bflo(u.z);
                    AT[(kk + 5) * 64 + n_l] = bfhi(u.z);
                    AT[(kk + 6) * 64 + n_l] = bflo(u.w);
                    AT[(kk + 7) * 64 + n_l] = bfhi(u.w);
                }
            } else {
                #pragma unroll
                for (int m = 0; m < 32; ++m) AT[(kb + m) * 64 + n_l] = 0.f;
            }
        }
        {
            const float* wsrc = Wf + (kc << 6);
            #pragma unroll
            for (int j = 0; j < 8; ++j) {
                const int idx = (t << 2) + (j << 10);
                *(float4*)(WC + idx) = *(const float4*)(wsrc + idx);
            }
        }
        __syncthreads();

        #pragma unroll 8
        for (int i = 0; i < 128; ++i) {
            const float4 av = *(const float4*)(AT + i * 64 + (tn << 2));
            const float4 bv = *(const float4*)(WC + i * 64 + (th << 2));
            acc[0][0] += av.x * bv.x; acc[0][1] += av.x * bv.y;
            acc[0][2] += av.x * bv.z; acc[0][3] += av.x * bv.w;
            acc[1][0] += av.y * bv.x; acc[1][1] += av.y * bv.y;
            acc[1][2] += av.y * bv.z; acc[1][3] += av.y * bv.w;
            acc[2][0] += av.z * bv.x; acc[2][1] += av.z * bv.y;
            acc[2][2] += av.z * bv.z; acc[2][3] += av.z * bv.w;
            acc[3][0] += av.w * bv.x; acc[3][1] += av.w * bv.y;
            acc[3][2] += av.w * bv.z; acc[3][3] += av.w * bv.w;
        }
        __syncthreads();
    }

    #pragma unroll
    for (int dn = 0; dn < 4; ++dn) {
        const int n = n_base + (tn << 2) + dn;
        if (n < nN) {
            float4 o;
            o.x = acc[dn][0]; o.y = acc[dn][1]; o.z = acc[dn][2]; o.w = acc[dn][3];
            *(float4*)(out + (size_t)n * CH + (th << 2)) = o;
        }
    }
}

// ---------------------------------------------------------------------------
// Fallback: per-edge direct with atomics.
// ---------------------------------------------------------------------------
__global__ __launch_bounds__(256) void rgcn_direct_kernel(
    const float* __restrict__ x, const float* __restrict__ W,
    const int* __restrict__ ei, const int* __restrict__ rel,
    float* __restrict__ out, int nE, int nWaves)
{
    const int w    = (int)((blockIdx.x * 256u + threadIdx.x) >> 6);
    const int lane = threadIdx.x & 63;

    for (int e = w; e < nE; e += nWaves) {
        const int src = ei[e];
        const int dst = ei[nE + e];
        const int r   = rel[e];
        const float* xrow = x + (size_t)src * CH;
        const float* wcol = W + ((size_t)r << 12) + lane;
        float acc = 0.f;
        #pragma unroll
        for (int i = 0; i < CH; ++i) acc += xrow[i] * wcol[i * CH];
        atomicAdd(out + (size_t)dst * CH + lane, acc);
    }
}

static inline size_t align256(size_t v) { return (v + 255) & ~(size_t)255; }

extern "C" void kernel_launch(void* const* d_in, const int* in_sizes, int n_in,
                              void* d_out, int out_size, void* d_ws, size_t ws_size,
                              hipStream_t stream) {
    const float* x   = (const float*)d_in[0];
    const float* W   = (const float*)d_in[1];
    const int*   ei  = (const int*)d_in[2];
    const int*   rel = (const int*)d_in[3];
    float*       out = (float*)d_out;

    const int nN = in_sizes[0] / CH;   // 50000
    const int nE = in_sizes[3];        // 1000000
    const int nK = nN * NREL;          // 400000
    const int NC = (nN + 255) >> 8;    // 196 coarse buckets

    // Workspace layout
    const size_t sz_A      = align256((size_t)nK * 32 * sizeof(uint32));        // 51.2 MB
    const size_t sz_xbf    = align256((size_t)nN * 32 * sizeof(uint32));        // 6.4 MB
    const size_t sz_start  = align256(((size_t)NC * 2048 + 2) * sizeof(int));   // 1.6 MB
    const size_t sz_binned = align256((size_t)nE * sizeof(uint32));             // 4 MB
    const size_t sz_sorted = align256((size_t)nE * sizeof(int));                // 4 MB
    const size_t sz_ccnt   = align256(256 * sizeof(int));
    const size_t sz_cbase  = align256(257 * sizeof(int));
    const size_t sz_ccur   = align256(256 * sizeof(int));
    const size_t need = sz_A + sz_xbf + sz_start + sz_binned + sz_sorted +
                        sz_ccnt + sz_cbase + sz_ccur;

    if (ws_size >= need && nN <= 65024 && NC <= 254) {
        char* p = (char*)d_ws;
        uint32* A      = (uint32*)p;  p += sz_A;
        uint32* xbf    = (uint32*)p;  p += sz_xbf;
        int*    start  = (int*)p;     p += sz_start;
        uint32* binned = (uint32*)p;  p += sz_binned;
        int*    sorted = (int*)p;     p += sz_sorted;
        int*    ccnt   = (int*)p;     p += sz_ccnt;
        int*    cbase  = (int*)p;     p += sz_cbase;
        int*    ccur   = (int*)p;

        hipMemsetAsync(ccnt, 0, 256 * sizeof(int), stream);

        const int n2 = nN * 32;
        xbf_k<<<(n2 + 255) / 256, 256, 0, stream>>>(x, xbf, n2);

        chist_k<<<256, 256, 0, stream>>>(ei, ccnt, nE, 256 * 256);
        cscan_k<<<1, 256, 0, stream>>>(ccnt, cbase, ccur, NC);
        bin_k<<<(nE + 2047) / 2048, 256, 0, stream>>>(ei, rel, ccur, binned, nE);
        fsort_k<<<NC, 1024, 0, stream>>>(binned, cbase, start, sorted, NC);

        const int aggBlocks = (nN + 7) / 8;    // one half-wave per node
        agg_k<<<aggBlocks, 256, 0, stream>>>(xbf, start, sorted, A, nN);

        gemm_k<<<(nN + 63) / 64, 256, 0, stream>>>(A, W, out, nN);
    } else {
        hipMemsetAsync(out, 0, (size_t)out_size * sizeof(float), stream);
        const int blocks = 2048;
        const int nWaves = blocks * (256 / 64);
        rgcn_direct_kernel<<<blocks, 256, 0, stream>>>(x, W, ei, rel, out, nE, nWaves);
    }
}

// Round 9
// 108.921 us; speedup vs baseline: 2.1113x; 1.3582x over previous
//
#include <hip/hip_runtime.h>
#include <hip/hip_bf16.h>

#define NREL 8
#define CH   64   // IN_CH == HID_CH == 64

typedef unsigned int uint32;
typedef __attribute__((ext_vector_type(8))) short bf16x8;
typedef __attribute__((ext_vector_type(4))) float f32x4;
union U4 { uint4 u; bf16x8 v; };

// ---- bf16 helpers (RNE) ----------------------------------------------------
static __device__ __forceinline__ uint32 packbf(float a, float b) {
    uint32 ua = __float_as_uint(a), ub = __float_as_uint(b);
    ua = (ua + 0x7fffu + ((ua >> 16) & 1u)) >> 16;          // low half  (elem 0 = even k)
    ub = (ub + 0x7fffu + ((ub >> 16) & 1u)) & 0xffff0000u;  // high half (elem 1 = odd k)
    return ua | ub;
}
static __device__ __forceinline__ float bflo(uint32 w) { return __uint_as_float(w << 16); }
static __device__ __forceinline__ float bfhi(uint32 w) { return __uint_as_float(w & 0xffff0000u); }

// ---------------------------------------------------------------------------
// xbf[n][cp] = packed bf16 pair of x[n][2cp..2cp+1]  (cp = 0..31)
// ---------------------------------------------------------------------------
__global__ __launch_bounds__(256) void xbf_k(
    const float* __restrict__ x, uint32* __restrict__ xbf, int n2)
{
    const int i = blockIdx.x * 256 + threadIdx.x;
    if (i < n2) {
        const float2 v = ((const float2*)x)[i];
        xbf[i] = packbf(v.x, v.y);
    }
}

// ---------------------------------------------------------------------------
// B-fragment prep: Bfrag[((ks*4+c)*64+lane)*4 + j2] packs
// W[ks*32+(lane>>4)*8+2j2 .. +1][c*16+(lane&15)] as bf16 pair.
// Same lane->k mapping as the A side, so any k-permutation assumption cancels.
// ---------------------------------------------------------------------------
__global__ __launch_bounds__(256) void bprep_k(
    const float* __restrict__ Wf, uint32* __restrict__ Bfrag)
{
    const int idx  = blockIdx.x * 256 + threadIdx.x;   // 0..4095
    const int lane = idx & 63;
    const int c    = (idx >> 6) & 3;
    const int ks   = idx >> 8;                          // 0..15
    const int col  = c * 16 + (lane & 15);
    const int k0   = ks * 32 + (lane >> 4) * 8;

    uint4 o;
    o.x = packbf(Wf[(k0 + 0) * 64 + col], Wf[(k0 + 1) * 64 + col]);
    o.y = packbf(Wf[(k0 + 2) * 64 + col], Wf[(k0 + 3) * 64 + col]);
    o.z = packbf(Wf[(k0 + 4) * 64 + col], Wf[(k0 + 5) * 64 + col]);
    o.w = packbf(Wf[(k0 + 6) * 64 + col], Wf[(k0 + 7) * 64 + col]);
    *(uint4*)(Bfrag + (size_t)idx * 4) = o;
}

// ---------------------------------------------------------------------------
// Coarse histogram over c = dst>>8 (NC buckets). LDS-staged.
// ---------------------------------------------------------------------------
__global__ __launch_bounds__(256) void chist_k(
    const int* __restrict__ ei, int* __restrict__ ccnt, int nE, int nT)
{
    __shared__ int h[256];
    h[threadIdx.x] = 0;
    __syncthreads();
    for (int e = blockIdx.x * 256 + threadIdx.x; e < nE; e += nT)
        atomicAdd(&h[ei[nE + e] >> 8], 1);
    __syncthreads();
    const int c = threadIdx.x;
    if (h[c]) atomicAdd(&ccnt[c], h[c]);
}

// ---------------------------------------------------------------------------
// Coarse exclusive scan (NC <= 256), fills cbase[0..NC] and ccur.
// ---------------------------------------------------------------------------
__global__ __launch_bounds__(256) void cscan_k(
    const int* __restrict__ ccnt, int* __restrict__ cbase,
    int* __restrict__ ccur, int NC)
{
    __shared__ int sc[256];
    const int t = threadIdx.x;
    const int v = (t < NC) ? ccnt[t] : 0;
    sc[t] = v;
    __syncthreads();
    for (int off = 1; off < 256; off <<= 1) {
        int add = (t >= off) ? sc[t - off] : 0;
        __syncthreads();
        sc[t] += add;
        __syncthreads();
    }
    const int ex = sc[t] - v;
    if (t < NC) { cbase[t] = ex; ccur[t] = ex; }
    if (t == 255) cbase[NC] = sc[255];
}

// ---------------------------------------------------------------------------
// Coarse binning: per 2048-edge chunk, stage in LDS, reserve runs, write runs.
// Entry pack: (dlow<<24)|(rel<<16)|src.
// ---------------------------------------------------------------------------
__global__ __launch_bounds__(256) void bin_k(
    const int* __restrict__ ei, const int* __restrict__ rel,
    int* __restrict__ ccur, uint32* __restrict__ binned, int nE)
{
    __shared__ uint32        ent[2048];
    __shared__ unsigned char cid[2048];
    __shared__ int lh[256], lb[256], lc[256];

    const int t = threadIdx.x;
    lh[t] = 0;
    __syncthreads();

    const int base = blockIdx.x * 2048;
    #pragma unroll
    for (int i = 0; i < 8; ++i) {
        const int idx = t + i * 256;
        const int e   = base + idx;
        if (e < nE) {
            const int dst = ei[nE + e];
            ent[idx] = ((uint32)(dst & 255) << 24) | ((uint32)rel[e] << 16) | (uint32)ei[e];
            const int c = dst >> 8;
            cid[idx] = (unsigned char)c;
            atomicAdd(&lh[c], 1);
        } else {
            cid[idx] = 255;   // sentinel (NC <= 254 guard in launcher)
        }
    }
    __syncthreads();

    if (lh[t]) lb[t] = atomicAdd(&ccur[t], lh[t]);
    lc[t] = 0;
    __syncthreads();

    #pragma unroll
    for (int i = 0; i < 8; ++i) {
        const int idx = t + i * 256;
        const int c   = cid[idx];
        if (c != 255) {
            const int off = atomicAdd(&lc[c], 1);
            binned[lb[c] + off] = ent[idx];
        }
    }
}

// ---------------------------------------------------------------------------
// Fine sort within one coarse bucket (keyspace 2048 = dlow*8+rel), in LDS.
// sorted[] keeps (rel<<16)|src for flush-on-rel-change aggregation.
// ---------------------------------------------------------------------------
__global__ __launch_bounds__(1024) void fsort_k(
    const uint32* __restrict__ binned, const int* __restrict__ cbase,
    int* __restrict__ start, int* __restrict__ sorted, int NC)
{
    __shared__ int fh[2048], fex[2048], fcur[2048], sc[1024];
    const int c  = blockIdx.x;
    const int t  = threadIdx.x;
    const int n0 = cbase[c];
    const int n1 = cbase[c + 1];

    fh[t] = 0; fh[t + 1024] = 0;
    __syncthreads();

    for (int j = n0 + t; j < n1; j += 1024) {
        const uint32 en = binned[j];
        atomicAdd(&fh[((en >> 24) << 3) | ((en >> 16) & 7)], 1);
    }
    __syncthreads();

    const int a = fh[2 * t], b = fh[2 * t + 1];
    sc[t] = a + b;
    __syncthreads();
    for (int off = 1; off < 1024; off <<= 1) {
        int add = (t >= off) ? sc[t - off] : 0;
        __syncthreads();
        sc[t] += add;
        __syncthreads();
    }
    const int ep = sc[t] - (a + b);
    fex[2 * t] = ep; fex[2 * t + 1] = ep + a;
    __syncthreads();

    fcur[t] = fex[t]; fcur[t + 1024] = fex[t + 1024];
    {
        const int k0 = c << 11;
        start[k0 + t]        = n0 + fex[t];
        start[k0 + t + 1024] = n0 + fex[t + 1024];
    }
    if (c == NC - 1 && t == 0) start[NC << 11] = n1;
    __syncthreads();

    for (int j = n0 + t; j < n1; j += 1024) {
        const uint32 en = binned[j];
        const int fk  = ((en >> 24) << 3) | ((en >> 16) & 7);
        const int off = atomicAdd(&fcur[fk], 1);
        sorted[n0 + off] = (int)(en & 0x7FFFFu);   // (rel<<16)|src
    }
}

// ---------------------------------------------------------------------------
// Aggregate v4: one HALF-WAVE per dst node, flat 4-unrolled run-length loop.
// ---------------------------------------------------------------------------
#define AGG_PROCESS(eu, uu)                                            \
    {                                                                  \
        const int r_ = (int)((eu) >> 16);                              \
        if (r_ != prev) {                                              \
            if (prev >= 0)                                             \
                A[(size_t)(kb + prev) * 32 + l32] = packbf(a0, a1);    \
            a0 = 0.f; a1 = 0.f;                                        \
            prev = r_;                                                 \
            seen |= (1u << r_);                                        \
        }                                                              \
        a0 += bflo(uu); a1 += bfhi(uu);                                \
    }

__global__ __launch_bounds__(256) void agg_k(
    const uint32* __restrict__ xbf, const int* __restrict__ start,
    const int* __restrict__ sorted, uint32* __restrict__ A, int nN)
{
    const int n = (int)((blockIdx.x * 256u + threadIdx.x) >> 5);   // half-wave id
    if (n >= nN) return;
    const int l32 = threadIdx.x & 31;
    const int kb  = n * NREL;

    const int b0 = start[kb];
    const int b8 = start[kb + 8];

    int   prev = -1;
    float a0 = 0.f, a1 = 0.f;
    unsigned seen = 0;

    int j = b0;
    for (; j + 4 <= b8; j += 4) {
        const uint32 e0 = (uint32)sorted[j];
        const uint32 e1 = (uint32)sorted[j + 1];
        const uint32 e2 = (uint32)sorted[j + 2];
        const uint32 e3 = (uint32)sorted[j + 3];
        const uint32 u0 = xbf[(size_t)(e0 & 0xFFFFu) * 32 + l32];
        const uint32 u1 = xbf[(size_t)(e1 & 0xFFFFu) * 32 + l32];
        const uint32 u2 = xbf[(size_t)(e2 & 0xFFFFu) * 32 + l32];
        const uint32 u3 = xbf[(size_t)(e3 & 0xFFFFu) * 32 + l32];
        AGG_PROCESS(e0, u0);
        AGG_PROCESS(e1, u1);
        AGG_PROCESS(e2, u2);
        AGG_PROCESS(e3, u3);
    }
    for (; j < b8; ++j) {
        const uint32 e = (uint32)sorted[j];
        const uint32 u = xbf[(size_t)(e & 0xFFFFu) * 32 + l32];
        AGG_PROCESS(e, u);
    }

    if (prev >= 0)
        A[(size_t)(kb + prev) * 32 + l32] = packbf(a0, a1);

    #pragma unroll
    for (int r = 0; r < NREL; ++r)
        if (!(seen & (1u << r)))
            A[(size_t)(kb + r) * 32 + l32] = 0u;
}

// ---------------------------------------------------------------------------
// GEMM v2 (MFMA): out[nN,64] = A[nN,512](bf16) @ W(bf16 frags). One wave per
// 32 rows (two 16-row tiles x 4 col-tiles), no LDS, no barriers. A rows are
// read as 16x16x32 A-fragments directly (lane&15 = row, lane>>4 = k-quad);
// B-fragments pre-swizzled by bprep_k. C/D layout per m89: col=lane&15,
// row=(lane>>4)*4+reg.
// ---------------------------------------------------------------------------
__global__ __launch_bounds__(256) void gemm_k(
    const uint32* __restrict__ A, const uint32* __restrict__ Bfrag,
    float* __restrict__ out, int nN)
{
    const int wv   = (int)((blockIdx.x * 256u + threadIdx.x) >> 6);
    const int lane = threadIdx.x & 63;
    const int n0   = wv * 32;
    if (n0 >= nN) return;

    const int rl = lane & 15;
    const int kq = lane >> 4;

    int r0 = n0 + rl;      if (r0 >= nN) r0 = nN - 1;
    int r1 = n0 + 16 + rl; if (r1 >= nN) r1 = nN - 1;
    const uint32* a0p = A + (size_t)r0 * 256 + kq * 4;
    const uint32* a1p = A + (size_t)r1 * 256 + kq * 4;
    const uint32* bp  = Bfrag + (size_t)lane * 4;

    f32x4 acc[2][4];
    #pragma unroll
    for (int t = 0; t < 2; ++t)
        #pragma unroll
        for (int c = 0; c < 4; ++c)
            acc[t][c] = (f32x4){0.f, 0.f, 0.f, 0.f};

    #pragma unroll 4
    for (int ks = 0; ks < 16; ++ks) {
        U4 ua0, ua1;
        ua0.u = *(const uint4*)(a0p + ks * 16);
        ua1.u = *(const uint4*)(a1p + ks * 16);
        #pragma unroll
        for (int c = 0; c < 4; ++c) {
            U4 ub;
            ub.u = *(const uint4*)(bp + ((size_t)(ks * 4 + c)) * 256);
            acc[0][c] = __builtin_amdgcn_mfma_f32_16x16x32_bf16(ua0.v, ub.v, acc[0][c], 0, 0, 0);
            acc[1][c] = __builtin_amdgcn_mfma_f32_16x16x32_bf16(ua1.v, ub.v, acc[1][c], 0, 0, 0);
        }
    }

    #pragma unroll
    for (int t = 0; t < 2; ++t)
        #pragma unroll
        for (int c = 0; c < 4; ++c)
            #pragma unroll
            for (int reg = 0; reg < 4; ++reg) {
                const int row = n0 + t * 16 + kq * 4 + reg;
                if (row < nN)
                    out[(size_t)row * 64 + c * 16 + rl] = acc[t][c][reg];
            }
}

// ---------------------------------------------------------------------------
// Fallback: per-edge direct with atomics.
// ---------------------------------------------------------------------------
__global__ __launch_bounds__(256) void rgcn_direct_kernel(
    const float* __restrict__ x, const float* __restrict__ W,
    const int* __restrict__ ei, const int* __restrict__ rel,
    float* __restrict__ out, int nE, int nWaves)
{
    const int w    = (int)((blockIdx.x * 256u + threadIdx.x) >> 6);
    const int lane = threadIdx.x & 63;

    for (int e = w; e < nE; e += nWaves) {
        const int src = ei[e];
        const int dst = ei[nE + e];
        const int r   = rel[e];
        const float* xrow = x + (size_t)src * CH;
        const float* wcol = W + ((size_t)r << 12) + lane;
        float acc = 0.f;
        #pragma unroll
        for (int i = 0; i < CH; ++i) acc += xrow[i] * wcol[i * CH];
        atomicAdd(out + (size_t)dst * CH + lane, acc);
    }
}

static inline size_t align256(size_t v) { return (v + 255) & ~(size_t)255; }

extern "C" void kernel_launch(void* const* d_in, const int* in_sizes, int n_in,
                              void* d_out, int out_size, void* d_ws, size_t ws_size,
                              hipStream_t stream) {
    const float* x   = (const float*)d_in[0];
    const float* W   = (const float*)d_in[1];
    const int*   ei  = (const int*)d_in[2];
    const int*   rel = (const int*)d_in[3];
    float*       out = (float*)d_out;

    const int nN = in_sizes[0] / CH;   // 50000
    const int nE = in_sizes[3];        // 1000000
    const int nK = nN * NREL;          // 400000
    const int NC = (nN + 255) >> 8;    // 196 coarse buckets

    // Workspace layout
    const size_t sz_A      = align256((size_t)nK * 32 * sizeof(uint32));        // 51.2 MB
    const size_t sz_xbf    = align256((size_t)nN * 32 * sizeof(uint32));        // 6.4 MB
    const size_t sz_start  = align256(((size_t)NC * 2048 + 2) * sizeof(int));   // 1.6 MB
    const size_t sz_binned = align256((size_t)nE * sizeof(uint32));             // 4 MB
    const size_t sz_sorted = align256((size_t)nE * sizeof(int));                // 4 MB
    const size_t sz_bfrag  = align256((size_t)16384 * sizeof(uint32));          // 64 KB
    const size_t sz_ccnt   = align256(256 * sizeof(int));
    const size_t sz_cbase  = align256(257 * sizeof(int));
    const size_t sz_ccur   = align256(256 * sizeof(int));
    const size_t need = sz_A + sz_xbf + sz_start + sz_binned + sz_sorted +
                        sz_bfrag + sz_ccnt + sz_cbase + sz_ccur;

    if (ws_size >= need && nN <= 65024 && NC <= 254) {
        char* p = (char*)d_ws;
        uint32* A      = (uint32*)p;  p += sz_A;
        uint32* xbf    = (uint32*)p;  p += sz_xbf;
        int*    start  = (int*)p;     p += sz_start;
        uint32* binned = (uint32*)p;  p += sz_binned;
        int*    sorted = (int*)p;     p += sz_sorted;
        uint32* Bfrag  = (uint32*)p;  p += sz_bfrag;
        int*    ccnt   = (int*)p;     p += sz_ccnt;
        int*    cbase  = (int*)p;     p += sz_cbase;
        int*    ccur   = (int*)p;

        hipMemsetAsync(ccnt, 0, 256 * sizeof(int), stream);

        const int n2 = nN * 32;
        xbf_k<<<(n2 + 255) / 256, 256, 0, stream>>>(x, xbf, n2);
        bprep_k<<<16, 256, 0, stream>>>(W, Bfrag);

        chist_k<<<256, 256, 0, stream>>>(ei, ccnt, nE, 256 * 256);
        cscan_k<<<1, 256, 0, stream>>>(ccnt, cbase, ccur, NC);
        bin_k<<<(nE + 2047) / 2048, 256, 0, stream>>>(ei, rel, ccur, binned, nE);
        fsort_k<<<NC, 1024, 0, stream>>>(binned, cbase, start, sorted, NC);

        const int aggBlocks = (nN + 7) / 8;    // one half-wave per node
        agg_k<<<aggBlocks, 256, 0, stream>>>(xbf, start, sorted, A, nN);

        const int gemmWaves  = (nN + 31) / 32;
        const int gemmBlocks = (gemmWaves + 3) / 4;
        gemm_k<<<gemmBlocks, 256, 0, stream>>>(A, Bfrag, out, nN);
    } else {
        hipMemsetAsync(out, 0, (size_t)out_size * sizeof(float), stream);
        const int blocks = 2048;
        const int nWaves = blocks * (256 / 64);
        rgcn_direct_kernel<<<blocks, 256, 0, stream>>>(x, W, ei, rel, out, nE, nWaves);
    }
}